// Round 11
// baseline (302.714 us; speedup 1.0000x reference)
//
#include <hip/hip_runtime.h>

// ---------------------------------------------------------------------------
// GraphSAGE (2-layer, mean aggregator), N=100000, E=1600000, D=128, fp32 out.
// R10: (a) aggregate reverted to R7's masked-fmaf 8-edge form (best measured:
// 57.5us; R8 subtract-dup and R9 predicated both regressed). (b) GEMM: 8-wave
// 512-thr blocks, ONE o-tile per wave -> ~124 VGPR (was ~160) and 2x waves;
// streaming-latency hiding was capped at ~12 waves/CU. (c) partition keeps
// R9's recorded-bucket flush (no binary search).
// ---------------------------------------------------------------------------

typedef unsigned int uint;
typedef unsigned short ushort;
using short8 = __attribute__((ext_vector_type(8))) short;
using f32x4  = __attribute__((ext_vector_type(4))) float;

__device__ __forceinline__ float bflo(uint u) { return __uint_as_float(u << 16); }
__device__ __forceinline__ float bfhi(uint u) { return __uint_as_float(u & 0xffff0000u); }
__device__ __forceinline__ ushort f2bf(float f) {
  uint u = __float_as_uint(f);
  return (ushort)((u + 0x7fffu + ((u >> 16) & 1u)) >> 16);
}

#define EPB 4096        // edges per partition block
#define NBKT_MAX 512    // buckets of 256 nodes; N<=131072
#define SLAB_CAP 5120   // slab capacity per bucket

__global__ __launch_bounds__(256) void f32_to_bf16_kernel(
    const float* __restrict__ in, ushort* __restrict__ out, int n4) {
  int i = blockIdx.x * 256 + threadIdx.x;
  if (i >= n4) return;
  float4 v = ((const float4*)in)[i];
  ushort4 r;
  r.x = f2bf(v.x); r.y = f2bf(v.y); r.z = f2bf(v.z); r.w = f2bf(v.w);
  ((ushort4*)out)[i] = r;
}

// One launch converts all 4 weight matrices (blockIdx.y selects matrix).
__global__ __launch_bounds__(256) void w_to_bf16_kernel(
    const float* __restrict__ w0, const float* __restrict__ w1,
    const float* __restrict__ w2, const float* __restrict__ w3,
    ushort* __restrict__ o0, ushort* __restrict__ o1,
    ushort* __restrict__ o2, ushort* __restrict__ o3, int n4) {
  int i = blockIdx.x * 256 + threadIdx.x;
  if (i >= n4) return;
  const float* in = (blockIdx.y == 0) ? w0 : (blockIdx.y == 1) ? w1
                    : (blockIdx.y == 2) ? w2 : w3;
  ushort* out = (blockIdx.y == 0) ? o0 : (blockIdx.y == 1) ? o1
                : (blockIdx.y == 2) ? o2 : o3;
  float4 v = ((const float4*)in)[i];
  ushort4 r;
  r.x = f2bf(v.x); r.y = f2bf(v.y); r.z = f2bf(v.z); r.w = f2bf(v.w);
  ((ushort4*)out)[i] = r;
}

__global__ __launch_bounds__(256) void partition_kernel(
    const int* __restrict__ src, const int* __restrict__ dst,
    int* __restrict__ bktcnt, uint* __restrict__ gpart, int E, int nbkt) {
  __shared__ uint staged[EPB];
  __shared__ ushort stagedb[EPB];     // bucket id per staged slot
  __shared__ int hist[NBKT_MAX];
  __shared__ int scanex[NBKT_MAX];
  __shared__ int lcur[NBKT_MAX];
  __shared__ int gbase[NBKT_MAX];
  __shared__ int s2[256];
  const int t = threadIdx.x;
  const int e0 = blockIdx.x * EPB;
  const int total = min(EPB, E - e0);

  hist[t] = 0; hist[t + 256] = 0;
  __syncthreads();

  int myb[16];
  uint myu[16];
#pragma unroll
  for (int q = 0; q < 16; ++q) {
    int e = e0 + q * 256 + t;
    if (e < E) {
      int s = src[e], d = dst[e];
      myb[q] = d >> 8;
      myu[q] = (uint)s | ((uint)(d & 255) << 24);
      atomicAdd(&hist[myb[q]], 1);
    } else {
      myb[q] = -1;
      myu[q] = 0;
    }
  }
  __syncthreads();

  int h0 = hist[2 * t], h1 = hist[2 * t + 1];
  s2[t] = h0 + h1;
  __syncthreads();
  for (int off = 1; off < 256; off <<= 1) {
    int v = (t >= off) ? s2[t - off] : 0;
    __syncthreads();
    s2[t] += v;
    __syncthreads();
  }
  int ex2 = s2[t] - (h0 + h1);
  scanex[2 * t] = ex2;
  scanex[2 * t + 1] = ex2 + h0;
  lcur[2 * t] = ex2;
  lcur[2 * t + 1] = ex2 + h0;
  __syncthreads();

#pragma unroll
  for (int q = 0; q < 2; ++q) {
    int b = t + q * 256;
    int c = hist[b];
    gbase[b] = (b < nbkt && c > 0)
                   ? (b * SLAB_CAP + atomicAdd(&bktcnt[b], c))
                   : 0;
  }

#pragma unroll
  for (int q = 0; q < 16; ++q) {
    if (myb[q] >= 0) {
      int p = atomicAdd(&lcur[myb[q]], 1);
      staged[p] = myu[q];
      stagedb[p] = (ushort)myb[q];
    }
  }
  __syncthreads();

  for (int i = t; i < total; i += 256) {
    int b = stagedb[i];
    gpart[gbase[b] + (i - scanex[b])] = staged[i];
  }
}

__global__ __launch_bounds__(512) void bucket_scan_kernel(
    const int* __restrict__ bktcnt, int* __restrict__ bucket_base,
    int* __restrict__ row_start, int nbkt, int n, int E) {
  __shared__ int sh[512];
  int t = threadIdx.x;
  int v = (t < nbkt) ? bktcnt[t] : 0;
  sh[t] = v;
  __syncthreads();
  for (int off = 1; off < 512; off <<= 1) {
    int u = (t >= off) ? sh[t - off] : 0;
    __syncthreads();
    sh[t] += u;
    __syncthreads();
  }
  if (t < nbkt) bucket_base[t] = sh[t] - v;
  if (t == 0) row_start[n] = E;
}

__global__ __launch_bounds__(256) void fine_fill_kernel(
    const uint* __restrict__ gpart, const int* __restrict__ bktcnt,
    const int* __restrict__ bucket_base, int* __restrict__ row_start,
    int* __restrict__ csr, int n) {
  __shared__ int hist[256];
  __shared__ int pfx[256];
  __shared__ int lcur[256];
  const int b = blockIdx.x;
  const int t = threadIdx.x;
  const int cnt = bktcnt[b];
  const uint* sl = gpart + (size_t)b * SLAB_CAP;
  hist[t] = 0;
  __syncthreads();
  for (int i = t; i < cnt; i += 256) atomicAdd(&hist[sl[i] >> 24], 1);
  __syncthreads();
  int h = hist[t];
  pfx[t] = h;
  __syncthreads();
  for (int off = 1; off < 256; off <<= 1) {
    int u = (t >= off) ? pfx[t - off] : 0;
    __syncthreads();
    pfx[t] += u;
    __syncthreads();
  }
  const int base = bucket_base[b] + pfx[t] - h;
  const int n0 = b << 8;
  if (n0 + t < n) row_start[n0 + t] = base;
  lcur[t] = base;
  __syncthreads();
  for (int i = t; i < cnt; i += 256) {
    uint u = sl[i];
    int p = atomicAdd(&lcur[u >> 24], 1);
    csr[p] = (int)(u & 0xFFFFFFu);
  }
}

// Half-wave (32 lanes) per node, bf16 in AND out. R7 form (best measured):
// fully batched masked 8-edge groups, clamped dup loads are L1-served.
__global__ __launch_bounds__(256) void aggregate_mean_bf16_kernel(
    const ushort* __restrict__ hb, const int* __restrict__ csr,
    const int* __restrict__ row_start, ushort* __restrict__ outb, int n) {
  int node = (blockIdx.x * 256 + threadIdx.x) >> 5;
  int lane = threadIdx.x & 31;
  if (node >= n) return;
  int e0 = row_start[node], e1 = row_start[node + 1];
  float a0 = 0.f, a1 = 0.f, a2 = 0.f, a3 = 0.f;
  if (e1 > e0) {
    const int elast = e1 - 1;
    for (int j0 = e0; j0 < e1; j0 += 8) {
      uint2 v[8];
      float m[8];
#pragma unroll
      for (int q = 0; q < 8; ++q) {
        int j = j0 + q;
        int jc = (j <= elast) ? j : elast;
        int s = csr[jc];
        v[q] = *(const uint2*)(hb + (size_t)s * 128 + lane * 4);
        m[q] = (j <= elast) ? 1.0f : 0.0f;
      }
#pragma unroll
      for (int q = 0; q < 8; ++q) {
        a0 = fmaf(bflo(v[q].x), m[q], a0);
        a1 = fmaf(bfhi(v[q].x), m[q], a1);
        a2 = fmaf(bflo(v[q].y), m[q], a2);
        a3 = fmaf(bfhi(v[q].y), m[q], a3);
      }
    }
    float inv = 1.0f / (float)(e1 - e0);
    a0 *= inv; a1 *= inv; a2 *= inv; a3 *= inv;
  }
  uint2 r;
  r.x = (uint)f2bf(a0) | ((uint)f2bf(a1) << 16);
  r.y = (uint)f2bf(a2) | ((uint)f2bf(a3) << 16);
  *(uint2*)(outb + (size_t)node * 128 + lane * 4) = r;
}

// MFMA SAGE GEMM v3: 512-thr block = 8 waves; block = 128 nodes x 128 outs.
// Wave w owns ONE o-tile (w*16..w*16+15); B-frags 8 short8 = 32 VGPR ->
// ~124 VGPR total -> 4 waves/SIMD eligible (2x the v2 occupancy).
// A-frags double-buffered in NAMED registers (rule #20), shared via L1/L2.
template <int RELU, int OUT_BF16>
__global__ __launch_bounds__(512) void sage_gemm_mfma_kernel(
    const ushort* __restrict__ hs, const ushort* __restrict__ hn,
    const ushort* __restrict__ Wsb, const ushort* __restrict__ Wnb,
    const float* __restrict__ bias, void* __restrict__ out_, int n) {
  const int w = threadIdx.x >> 6;     // 0..7 -> o-tile
  const int lane = threadIdx.x & 63;
  const int lr = lane & 15;
  const int lk = (lane >> 4) * 8;
  const int m0 = blockIdx.x * 128;
  if (m0 >= n) return;

  short8 bs[4], bn[4];
  const int oc = w * 16 + lr;
  {
    const ushort* qs = Wsb + (size_t)oc * 128 + lk;
    const ushort* qn = Wnb + (size_t)oc * 128 + lk;
#pragma unroll
    for (int s = 0; s < 4; ++s) {
      bs[s] = *(const short8*)(qs + s * 32);
      bn[s] = *(const short8*)(qn + s * 32);
    }
  }
  const float bv = bias[oc];

  short8 as0[4], an0[4], as1[4], an1[4];  // named A double-buffer (rule #20)

#define LOAD_A(mt, AS, AN)                                          \
  {                                                                 \
    int arow = m0 + (mt) * 16 + lr;                                 \
    if (arow >= n) arow = n - 1;                                    \
    const ushort* ps = hs + (size_t)arow * 128 + lk;                \
    const ushort* pq = hn + (size_t)arow * 128 + lk;                \
    _Pragma("unroll") for (int s = 0; s < 4; ++s) {                 \
      AS[s] = *(const short8*)(ps + s * 32);                        \
      AN[s] = *(const short8*)(pq + s * 32);                        \
    }                                                               \
  }

#define COMPUTE(mt, AS, AN)                                         \
  {                                                                 \
    const int mbase = m0 + (mt) * 16 + (lane >> 4) * 4;             \
    f32x4 acc = {0.f, 0.f, 0.f, 0.f};                               \
    _Pragma("unroll") for (int s = 0; s < 4; ++s)                   \
        acc = __builtin_amdgcn_mfma_f32_16x16x32_bf16(              \
            AS[s], bs[s], acc, 0, 0, 0);                            \
    _Pragma("unroll") for (int s = 0; s < 4; ++s)                   \
        acc = __builtin_amdgcn_mfma_f32_16x16x32_bf16(              \
            AN[s], bn[s], acc, 0, 0, 0);                            \
    _Pragma("unroll") for (int r = 0; r < 4; ++r) {                 \
      int node = mbase + r;                                         \
      if (node < n) {                                               \
        float v = acc[r] + bv;                                      \
        if (RELU) v = fmaxf(v, 0.f);                                \
        if (OUT_BF16)                                               \
          ((ushort*)out_)[(size_t)node * 128 + oc] = f2bf(v);       \
        else                                                        \
          ((float*)out_)[(size_t)node * 128 + oc] = v;              \
      }                                                             \
    }                                                               \
  }

  const int nmt = min(8, (n - m0 + 15) >> 4);
  LOAD_A(0, as0, an0);
  int mt = 0;
  for (; mt + 2 <= nmt; mt += 2) {
    LOAD_A(mt + 1, as1, an1);
    COMPUTE(mt, as0, an0);
    if (mt + 2 < nmt) LOAD_A(mt + 2, as0, an0);
    COMPUTE(mt + 1, as1, an1);
  }
  if (nmt & 1) COMPUTE(nmt - 1, as0, an0);
#undef LOAD_A
#undef COMPUTE
}

extern "C" void kernel_launch(void* const* d_in, const int* in_sizes, int n_in,
                              void* d_out, int out_size, void* d_ws, size_t ws_size,
                              hipStream_t stream) {
  const float* x   = (const float*)d_in[0];
  const int*   src = (const int*)d_in[1];
  const int*   dst = (const int*)d_in[2];
  const float* Ws1 = (const float*)d_in[3];
  const float* Wn1 = (const float*)d_in[4];
  const float* b1  = (const float*)d_in[5];
  const float* Ws2 = (const float*)d_in[6];
  const float* Wn2 = (const float*)d_in[7];
  const float* b2  = (const float*)d_in[8];
  float* out = (float*)d_out;
  const int D = 128;
  const int N = in_sizes[0] / D;
  const int E = in_sizes[1];
  (void)n_in; (void)out_size; (void)ws_size;

  char* p = (char*)d_ws;
  auto carve = [&](size_t bytes) {
    char* r = p;
    p += (bytes + 255) & ~(size_t)255;
    return r;
  };
  int*    bktcnt      = (int*)carve(NBKT_MAX * 4);
  int*    bucket_base = (int*)carve(NBKT_MAX * 4);
  int*    row_start   = (int*)carve((size_t)(N + 1) * 4);
  uint*   gpart       = (uint*)carve((size_t)NBKT_MAX * SLAB_CAP * 4);
  int*    csr         = (int*)carve((size_t)E * 4);
  ushort* xb          = (ushort*)carve((size_t)N * D * 2);
  ushort* h1b         = (ushort*)carve((size_t)N * D * 2);
  ushort* hnb         = (ushort*)carve((size_t)N * D * 2);
  ushort* Wsb1        = (ushort*)carve((size_t)D * D * 2);
  ushort* Wnb1        = (ushort*)carve((size_t)D * D * 2);
  ushort* Wsb2        = (ushort*)carve((size_t)D * D * 2);
  ushort* Wnb2        = (ushort*)carve((size_t)D * D * 2);

  hipMemsetAsync(bktcnt, 0, NBKT_MAX * 4, stream);

  const int nbkt = (N + 255) >> 8;
  const int wq = D * D / 4;

  f32_to_bf16_kernel<<<(N * D / 4 + 255) / 256, 256, 0, stream>>>(x, xb, N * D / 4);
  {
    dim3 g((wq + 255) / 256, 4);
    w_to_bf16_kernel<<<g, 256, 0, stream>>>(Ws1, Wn1, Ws2, Wn2,
                                            Wsb1, Wnb1, Wsb2, Wnb2, wq);
  }

  partition_kernel<<<(E + EPB - 1) / EPB, 256, 0, stream>>>(src, dst, bktcnt, gpart, E, nbkt);
  bucket_scan_kernel<<<1, 512, 0, stream>>>(bktcnt, bucket_base, row_start, nbkt, N, E);
  fine_fill_kernel<<<nbkt, 256, 0, stream>>>(gpart, bktcnt, bucket_base, row_start, csr, N);

  const int gblocks = (N + 127) / 128;

  aggregate_mean_bf16_kernel<<<(N + 7) / 8, 256, 0, stream>>>(xb, csr, row_start, hnb, N);
  sage_gemm_mfma_kernel<1, 1><<<gblocks, 512, 0, stream>>>(
      xb, hnb, Wsb1, Wnb1, b1, h1b, N);

  aggregate_mean_bf16_kernel<<<(N + 7) / 8, 256, 0, stream>>>(h1b, csr, row_start, hnb, N);
  sage_gemm_mfma_kernel<0, 0><<<gblocks, 512, 0, stream>>>(
      h1b, hnb, Wsb2, Wnb2, b2, out, N);
}

// Round 12
// 247.668 us; speedup vs baseline: 1.2223x; 1.2223x over previous
//
#include <hip/hip_runtime.h>

// ---------------------------------------------------------------------------
// GraphSAGE (2-layer, mean aggregator), N=100000, E=1600000, D=128, fp32 out.
// R11: (a) GEMM reverted to R6 form (4 waves, 2 o-tiles/wave — R10's 1-o-tile
// 8-wave halved arithmetic intensity and regressed 45->71us). (b) aggregate:
// 16B/lane paired gather — lanes 0-15 load edge j, lanes 16-31 edge j+1
// (uint4); half the load instructions of R7 at same bytes-in-flight and same
// dup rate; shfl_xor(16) combines halves. Masked-fmaf structure kept (R9's
// predication serialized; R8's 16-group added 47% requests).
// ---------------------------------------------------------------------------

typedef unsigned int uint;
typedef unsigned short ushort;
using short8 = __attribute__((ext_vector_type(8))) short;
using f32x4  = __attribute__((ext_vector_type(4))) float;

__device__ __forceinline__ float bflo(uint u) { return __uint_as_float(u << 16); }
__device__ __forceinline__ float bfhi(uint u) { return __uint_as_float(u & 0xffff0000u); }
__device__ __forceinline__ ushort f2bf(float f) {
  uint u = __float_as_uint(f);
  return (ushort)((u + 0x7fffu + ((u >> 16) & 1u)) >> 16);
}

#define EPB 4096        // edges per partition block
#define NBKT_MAX 512    // buckets of 256 nodes; N<=131072
#define SLAB_CAP 5120   // slab capacity per bucket

__global__ __launch_bounds__(256) void f32_to_bf16_kernel(
    const float* __restrict__ in, ushort* __restrict__ out, int n4) {
  int i = blockIdx.x * 256 + threadIdx.x;
  if (i >= n4) return;
  float4 v = ((const float4*)in)[i];
  ushort4 r;
  r.x = f2bf(v.x); r.y = f2bf(v.y); r.z = f2bf(v.z); r.w = f2bf(v.w);
  ((ushort4*)out)[i] = r;
}

// One launch converts all 4 weight matrices (blockIdx.y selects matrix).
__global__ __launch_bounds__(256) void w_to_bf16_kernel(
    const float* __restrict__ w0, const float* __restrict__ w1,
    const float* __restrict__ w2, const float* __restrict__ w3,
    ushort* __restrict__ o0, ushort* __restrict__ o1,
    ushort* __restrict__ o2, ushort* __restrict__ o3, int n4) {
  int i = blockIdx.x * 256 + threadIdx.x;
  if (i >= n4) return;
  const float* in = (blockIdx.y == 0) ? w0 : (blockIdx.y == 1) ? w1
                    : (blockIdx.y == 2) ? w2 : w3;
  ushort* out = (blockIdx.y == 0) ? o0 : (blockIdx.y == 1) ? o1
                : (blockIdx.y == 2) ? o2 : o3;
  float4 v = ((const float4*)in)[i];
  ushort4 r;
  r.x = f2bf(v.x); r.y = f2bf(v.y); r.z = f2bf(v.z); r.w = f2bf(v.w);
  ((ushort4*)out)[i] = r;
}

__global__ __launch_bounds__(256) void partition_kernel(
    const int* __restrict__ src, const int* __restrict__ dst,
    int* __restrict__ bktcnt, uint* __restrict__ gpart, int E, int nbkt) {
  __shared__ uint staged[EPB];
  __shared__ ushort stagedb[EPB];     // bucket id per staged slot
  __shared__ int hist[NBKT_MAX];
  __shared__ int scanex[NBKT_MAX];
  __shared__ int lcur[NBKT_MAX];
  __shared__ int gbase[NBKT_MAX];
  __shared__ int s2[256];
  const int t = threadIdx.x;
  const int e0 = blockIdx.x * EPB;
  const int total = min(EPB, E - e0);

  hist[t] = 0; hist[t + 256] = 0;
  __syncthreads();

  int myb[16];
  uint myu[16];
#pragma unroll
  for (int q = 0; q < 16; ++q) {
    int e = e0 + q * 256 + t;
    if (e < E) {
      int s = src[e], d = dst[e];
      myb[q] = d >> 8;
      myu[q] = (uint)s | ((uint)(d & 255) << 24);
      atomicAdd(&hist[myb[q]], 1);
    } else {
      myb[q] = -1;
      myu[q] = 0;
    }
  }
  __syncthreads();

  int h0 = hist[2 * t], h1 = hist[2 * t + 1];
  s2[t] = h0 + h1;
  __syncthreads();
  for (int off = 1; off < 256; off <<= 1) {
    int v = (t >= off) ? s2[t - off] : 0;
    __syncthreads();
    s2[t] += v;
    __syncthreads();
  }
  int ex2 = s2[t] - (h0 + h1);
  scanex[2 * t] = ex2;
  scanex[2 * t + 1] = ex2 + h0;
  lcur[2 * t] = ex2;
  lcur[2 * t + 1] = ex2 + h0;
  __syncthreads();

#pragma unroll
  for (int q = 0; q < 2; ++q) {
    int b = t + q * 256;
    int c = hist[b];
    gbase[b] = (b < nbkt && c > 0)
                   ? (b * SLAB_CAP + atomicAdd(&bktcnt[b], c))
                   : 0;
  }

#pragma unroll
  for (int q = 0; q < 16; ++q) {
    if (myb[q] >= 0) {
      int p = atomicAdd(&lcur[myb[q]], 1);
      staged[p] = myu[q];
      stagedb[p] = (ushort)myb[q];
    }
  }
  __syncthreads();

  for (int i = t; i < total; i += 256) {
    int b = stagedb[i];
    gpart[gbase[b] + (i - scanex[b])] = staged[i];
  }
}

__global__ __launch_bounds__(512) void bucket_scan_kernel(
    const int* __restrict__ bktcnt, int* __restrict__ bucket_base,
    int* __restrict__ row_start, int nbkt, int n, int E) {
  __shared__ int sh[512];
  int t = threadIdx.x;
  int v = (t < nbkt) ? bktcnt[t] : 0;
  sh[t] = v;
  __syncthreads();
  for (int off = 1; off < 512; off <<= 1) {
    int u = (t >= off) ? sh[t - off] : 0;
    __syncthreads();
    sh[t] += u;
    __syncthreads();
  }
  if (t < nbkt) bucket_base[t] = sh[t] - v;
  if (t == 0) row_start[n] = E;
}

__global__ __launch_bounds__(256) void fine_fill_kernel(
    const uint* __restrict__ gpart, const int* __restrict__ bktcnt,
    const int* __restrict__ bucket_base, int* __restrict__ row_start,
    int* __restrict__ csr, int n) {
  __shared__ int hist[256];
  __shared__ int pfx[256];
  __shared__ int lcur[256];
  const int b = blockIdx.x;
  const int t = threadIdx.x;
  const int cnt = bktcnt[b];
  const uint* sl = gpart + (size_t)b * SLAB_CAP;
  hist[t] = 0;
  __syncthreads();
  for (int i = t; i < cnt; i += 256) atomicAdd(&hist[sl[i] >> 24], 1);
  __syncthreads();
  int h = hist[t];
  pfx[t] = h;
  __syncthreads();
  for (int off = 1; off < 256; off <<= 1) {
    int u = (t >= off) ? pfx[t - off] : 0;
    __syncthreads();
    pfx[t] += u;
    __syncthreads();
  }
  const int base = bucket_base[b] + pfx[t] - h;
  const int n0 = b << 8;
  if (n0 + t < n) row_start[n0 + t] = base;
  lcur[t] = base;
  __syncthreads();
  for (int i = t; i < cnt; i += 256) {
    uint u = sl[i];
    int p = atomicAdd(&lcur[u >> 24], 1);
    csr[p] = (int)(u & 0xFFFFFFu);
  }
}

// Half-wave (32 lanes) per node, PAIRED 16B/lane gather: lanes 0-15 load
// edge j (uint4 = 8 dims), lanes 16-31 load edge j+1. 8-edge groups = 4
// load insts (R7: 8) at same bytes-in-flight; masked-fmaf (best measured
// form); shfl_xor(16) cross-half reduce; lanes 0-15 write the 256B row.
__global__ __launch_bounds__(256) void aggregate_mean_bf16_kernel(
    const ushort* __restrict__ hb, const int* __restrict__ csr,
    const int* __restrict__ row_start, ushort* __restrict__ outb, int n) {
  int node = (blockIdx.x * 256 + threadIdx.x) >> 5;
  int lane = threadIdx.x & 31;
  if (node >= n) return;
  const int sub = lane >> 4;       // edge parity handled by this lane
  const int dlo = (lane & 15) * 8; // dims dlo..dlo+7
  int e0 = row_start[node], e1 = row_start[node + 1];
  float a0 = 0.f, a1 = 0.f, a2 = 0.f, a3 = 0.f;
  float a4 = 0.f, a5 = 0.f, a6 = 0.f, a7 = 0.f;
  if (e1 > e0) {
    const int elast = e1 - 1;
    for (int j0 = e0; j0 < e1; j0 += 8) {
      uint4 v[4];
      float m[4];
#pragma unroll
      for (int q = 0; q < 4; ++q) {
        int j = j0 + 2 * q + sub;
        int jc = (j <= elast) ? j : elast;
        int s = csr[jc];
        v[q] = *(const uint4*)(hb + (size_t)s * 128 + dlo);
        m[q] = (j <= elast) ? 1.0f : 0.0f;
      }
#pragma unroll
      for (int q = 0; q < 4; ++q) {
        a0 = fmaf(bflo(v[q].x), m[q], a0);
        a1 = fmaf(bfhi(v[q].x), m[q], a1);
        a2 = fmaf(bflo(v[q].y), m[q], a2);
        a3 = fmaf(bfhi(v[q].y), m[q], a3);
        a4 = fmaf(bflo(v[q].z), m[q], a4);
        a5 = fmaf(bfhi(v[q].z), m[q], a5);
        a6 = fmaf(bflo(v[q].w), m[q], a6);
        a7 = fmaf(bfhi(v[q].w), m[q], a7);
      }
    }
    // combine even-edge and odd-edge partial sums (partner holds same dims)
    a0 += __shfl_xor(a0, 16, 64);
    a1 += __shfl_xor(a1, 16, 64);
    a2 += __shfl_xor(a2, 16, 64);
    a3 += __shfl_xor(a3, 16, 64);
    a4 += __shfl_xor(a4, 16, 64);
    a5 += __shfl_xor(a5, 16, 64);
    a6 += __shfl_xor(a6, 16, 64);
    a7 += __shfl_xor(a7, 16, 64);
    float inv = 1.0f / (float)(e1 - e0);
    a0 *= inv; a1 *= inv; a2 *= inv; a3 *= inv;
    a4 *= inv; a5 *= inv; a6 *= inv; a7 *= inv;
  }
  if (lane < 16) {
    uint4 r;
    r.x = (uint)f2bf(a0) | ((uint)f2bf(a1) << 16);
    r.y = (uint)f2bf(a2) | ((uint)f2bf(a3) << 16);
    r.z = (uint)f2bf(a4) | ((uint)f2bf(a5) << 16);
    r.w = (uint)f2bf(a6) | ((uint)f2bf(a7) << 16);
    *(uint4*)(outb + (size_t)node * 128 + dlo) = r;
  }
}

// MFMA SAGE GEMM v2 (R6 form, best measured): block = 128 nodes x 128 outs,
// 4 waves. Wave w owns o-tiles {w, w+4}; B-frags in registers all kernel.
// A-frags double-buffered in NAMED registers; 16 MFMA per m-tile per wave.
template <int RELU, int OUT_BF16>
__global__ __launch_bounds__(256) void sage_gemm_mfma_kernel(
    const ushort* __restrict__ hs, const ushort* __restrict__ hn,
    const ushort* __restrict__ Wsb, const ushort* __restrict__ Wnb,
    const float* __restrict__ bias, void* __restrict__ out_, int n) {
  const int w = threadIdx.x >> 6;
  const int lane = threadIdx.x & 63;
  const int lr = lane & 15;
  const int lk = (lane >> 4) * 8;
  const int m0 = blockIdx.x * 128;
  if (m0 >= n) return;

  short8 bs[2][4], bn[2][4];
  float bv[2];
  int oc[2];
#pragma unroll
  for (int u = 0; u < 2; ++u) {
    oc[u] = (w + u * 4) * 16 + lr;
    const ushort* qs = Wsb + (size_t)oc[u] * 128 + lk;
    const ushort* qn = Wnb + (size_t)oc[u] * 128 + lk;
#pragma unroll
    for (int s = 0; s < 4; ++s) {
      bs[u][s] = *(const short8*)(qs + s * 32);
      bn[u][s] = *(const short8*)(qn + s * 32);
    }
    bv[u] = bias[oc[u]];
  }

  short8 as0[4], an0[4], as1[4], an1[4];  // named A double-buffer (rule #20)

#define LOAD_A(mt, AS, AN)                                          \
  {                                                                 \
    int arow = m0 + (mt) * 16 + lr;                                 \
    if (arow >= n) arow = n - 1;                                    \
    const ushort* ps = hs + (size_t)arow * 128 + lk;                \
    const ushort* pq = hn + (size_t)arow * 128 + lk;                \
    _Pragma("unroll") for (int s = 0; s < 4; ++s) {                 \
      AS[s] = *(const short8*)(ps + s * 32);                        \
      AN[s] = *(const short8*)(pq + s * 32);                        \
    }                                                               \
  }

#define COMPUTE(mt, AS, AN)                                         \
  {                                                                 \
    const int mbase = m0 + (mt) * 16 + (lane >> 4) * 4;             \
    _Pragma("unroll") for (int u = 0; u < 2; ++u) {                 \
      f32x4 acc = {0.f, 0.f, 0.f, 0.f};                             \
      _Pragma("unroll") for (int s = 0; s < 4; ++s)                 \
          acc = __builtin_amdgcn_mfma_f32_16x16x32_bf16(            \
              AS[s], bs[u][s], acc, 0, 0, 0);                       \
      _Pragma("unroll") for (int s = 0; s < 4; ++s)                 \
          acc = __builtin_amdgcn_mfma_f32_16x16x32_bf16(            \
              AN[s], bn[u][s], acc, 0, 0, 0);                       \
      _Pragma("unroll") for (int r = 0; r < 4; ++r) {               \
        int node = mbase + r;                                       \
        if (node < n) {                                             \
          float v = acc[r] + bv[u];                                 \
          if (RELU) v = fmaxf(v, 0.f);                              \
          if (OUT_BF16)                                             \
            ((ushort*)out_)[(size_t)node * 128 + oc[u]] = f2bf(v);  \
          else                                                      \
            ((float*)out_)[(size_t)node * 128 + oc[u]] = v;         \
        }                                                           \
      }                                                             \
    }                                                               \
  }

  const int nmt = min(8, (n - m0 + 15) >> 4);
  LOAD_A(0, as0, an0);
  int mt = 0;
  for (; mt + 2 <= nmt; mt += 2) {
    LOAD_A(mt + 1, as1, an1);
    COMPUTE(mt, as0, an0);
    if (mt + 2 < nmt) LOAD_A(mt + 2, as0, an0);
    COMPUTE(mt + 1, as1, an1);
  }
  if (nmt & 1) COMPUTE(nmt - 1, as0, an0);
#undef LOAD_A
#undef COMPUTE
}

extern "C" void kernel_launch(void* const* d_in, const int* in_sizes, int n_in,
                              void* d_out, int out_size, void* d_ws, size_t ws_size,
                              hipStream_t stream) {
  const float* x   = (const float*)d_in[0];
  const int*   src = (const int*)d_in[1];
  const int*   dst = (const int*)d_in[2];
  const float* Ws1 = (const float*)d_in[3];
  const float* Wn1 = (const float*)d_in[4];
  const float* b1  = (const float*)d_in[5];
  const float* Ws2 = (const float*)d_in[6];
  const float* Wn2 = (const float*)d_in[7];
  const float* b2  = (const float*)d_in[8];
  float* out = (float*)d_out;
  const int D = 128;
  const int N = in_sizes[0] / D;
  const int E = in_sizes[1];
  (void)n_in; (void)out_size; (void)ws_size;

  char* p = (char*)d_ws;
  auto carve = [&](size_t bytes) {
    char* r = p;
    p += (bytes + 255) & ~(size_t)255;
    return r;
  };
  int*    bktcnt      = (int*)carve(NBKT_MAX * 4);
  int*    bucket_base = (int*)carve(NBKT_MAX * 4);
  int*    row_start   = (int*)carve((size_t)(N + 1) * 4);
  uint*   gpart       = (uint*)carve((size_t)NBKT_MAX * SLAB_CAP * 4);
  int*    csr         = (int*)carve((size_t)E * 4);
  ushort* xb          = (ushort*)carve((size_t)N * D * 2);
  ushort* h1b         = (ushort*)carve((size_t)N * D * 2);
  ushort* hnb         = (ushort*)carve((size_t)N * D * 2);
  ushort* Wsb1        = (ushort*)carve((size_t)D * D * 2);
  ushort* Wnb1        = (ushort*)carve((size_t)D * D * 2);
  ushort* Wsb2        = (ushort*)carve((size_t)D * D * 2);
  ushort* Wnb2        = (ushort*)carve((size_t)D * D * 2);

  hipMemsetAsync(bktcnt, 0, NBKT_MAX * 4, stream);

  const int nbkt = (N + 255) >> 8;
  const int wq = D * D / 4;

  f32_to_bf16_kernel<<<(N * D / 4 + 255) / 256, 256, 0, stream>>>(x, xb, N * D / 4);
  {
    dim3 g((wq + 255) / 256, 4);
    w_to_bf16_kernel<<<g, 256, 0, stream>>>(Ws1, Wn1, Ws2, Wn2,
                                            Wsb1, Wnb1, Wsb2, Wnb2, wq);
  }

  partition_kernel<<<(E + EPB - 1) / EPB, 256, 0, stream>>>(src, dst, bktcnt, gpart, E, nbkt);
  bucket_scan_kernel<<<1, 512, 0, stream>>>(bktcnt, bucket_base, row_start, nbkt, N, E);
  fine_fill_kernel<<<nbkt, 256, 0, stream>>>(gpart, bktcnt, bucket_base, row_start, csr, N);

  const int gblocks = (N + 127) / 128;

  aggregate_mean_bf16_kernel<<<(N + 7) / 8, 256, 0, stream>>>(xb, csr, row_start, hnb, N);
  sage_gemm_mfma_kernel<1, 1><<<gblocks, 256, 0, stream>>>(
      xb, hnb, Wsb1, Wnb1, b1, h1b, N);

  aggregate_mean_bf16_kernel<<<(N + 7) / 8, 256, 0, stream>>>(h1b, csr, row_start, hnb, N);
  sage_gemm_mfma_kernel<0, 0><<<gblocks, 256, 0, stream>>>(
      h1b, hnb, Wsb2, Wnb2, b2, out, N);
}